// Round 2
// baseline (1162.352 us; speedup 1.0000x reference)
//
#include <hip/hip_runtime.h>

typedef __bf16 bf16;
typedef __bf16 bf16x8 __attribute__((ext_vector_type(8)));
typedef __bf16 bf16x4 __attribute__((ext_vector_type(4)));
typedef float  floatx4 __attribute__((ext_vector_type(4)));

#define HIDDEN   2048
#define NUMH     64
#define HDIM     64
#define STATE    128
#define INTER    4096
#define CONV_DIM 4352
#define PROJ_N   8512
#define PROJ_PAD 8576
#define SEQ      2048
#define BATCH    2
#define CHUNK    256
#define NCHUNK   8
#define ROWS     4096   // BATCH*SEQ
#define DT_COL0  8448   // INTER + CONV_DIM

// ---------------------------------------------------------------- f32 -> bf16
__global__ __launch_bounds__(256) void cvt_bf16_kernel(
    const float* __restrict__ in, bf16* __restrict__ out, long n, long srcn) {
  long i = ((long)blockIdx.x * 256 + threadIdx.x) * 4;
  if (i >= n) return;
  if (i + 3 < srcn) {
    const float* p = in + i;
    bf16x4 o;
    o[0] = (bf16)p[0]; o[1] = (bf16)p[1]; o[2] = (bf16)p[2]; o[3] = (bf16)p[3];
    *(bf16x4*)(out + i) = o;
  } else {
    for (int j = 0; j < 4; j++) {
      float v = (i + j < srcn) ? in[i + j] : 0.f;
      out[i + j] = (bf16)v;
    }
  }
}

// ------------------------------------------------------- bf16 MFMA GEMM (BT)
// C[M][N] = A[M][K] @ B[N][K]^T + bias
// Cb!=null -> bf16 output; else f32 to Cf. ds: f32 side-copy of cols
// [dt0, dt0+64) (dt columns need full precision downstream).
__global__ __launch_bounds__(256, 2) void gemm_bt_kernel(
    const bf16* __restrict__ A, const bf16* __restrict__ B,
    const float* __restrict__ bias, bf16* __restrict__ Cb,
    float* __restrict__ Cf, float* __restrict__ ds,
    int M, int N, int K, int bias_n, int dt0) {
  __shared__ __align__(16) bf16 lA[128 * 32];
  __shared__ __align__(16) bf16 lB[128 * 32];
  const int tid  = threadIdx.x;
  const int lane = tid & 63;
  const int wave = tid >> 6;
  const int m0 = blockIdx.y * 128;
  const int n0 = blockIdx.x * 128;
  const int wm = (wave >> 1) * 64;
  const int wn = (wave & 1) * 64;
  const int q  = lane >> 4;     // 0..3
  const int ln = lane & 15;
  const int r0 = tid >> 2;      // 0..63
  const int c0 = (tid & 3) * 8; // 0,8,16,24

  floatx4 acc[4][4] = {};

  const bf16* Ap = A + (long)(m0 + r0) * K + c0;
  const bf16* Bp = B + (long)(n0 + r0) * K + c0;

  for (int k0 = 0; k0 < K; k0 += 32) {
    bf16x8 a0 = *(const bf16x8*)(Ap + k0);
    bf16x8 a1 = *(const bf16x8*)(Ap + (long)64 * K + k0);
    bf16x8 b0 = *(const bf16x8*)(Bp + k0);
    bf16x8 b1 = *(const bf16x8*)(Bp + (long)64 * K + k0);
    __syncthreads();
    *(bf16x8*)(lA + r0 * 32 + c0)        = a0;
    *(bf16x8*)(lA + (r0 + 64) * 32 + c0) = a1;
    *(bf16x8*)(lB + r0 * 32 + c0)        = b0;
    *(bf16x8*)(lB + (r0 + 64) * 32 + c0) = b1;
    __syncthreads();
    bf16x8 af[4], bg[4];
#pragma unroll
    for (int i = 0; i < 4; i++) {
      af[i] = *(const bf16x8*)(lA + (wm + i * 16 + ln) * 32 + q * 8);
      bg[i] = *(const bf16x8*)(lB + (wn + i * 16 + ln) * 32 + q * 8);
    }
#pragma unroll
    for (int mi = 0; mi < 4; mi++)
#pragma unroll
      for (int ni = 0; ni < 4; ni++)
        acc[mi][ni] = __builtin_amdgcn_mfma_f32_16x16x32_bf16(
            af[mi], bg[ni], acc[mi][ni], 0, 0, 0);
  }

#pragma unroll
  for (int mi = 0; mi < 4; mi++) {
#pragma unroll
    for (int ni = 0; ni < 4; ni++) {
      int col = n0 + wn + ni * 16 + ln;
      float bv = (col < bias_n) ? bias[col] : 0.f;
#pragma unroll
      for (int r = 0; r < 4; r++) {
        int row = m0 + wm + mi * 16 + q * 4 + r;
        float v = acc[mi][ni][r] + bv;
        if (Cb) Cb[(long)row * N + col] = (bf16)v;
        else    Cf[(long)row * N + col] = v;
        if (ds && col >= dt0 && col < dt0 + 64)
          ds[(long)row * 64 + (col - dt0)] = v;
      }
    }
  }
}

// ------------------------------------------------------- causal conv4 + SiLU
__global__ __launch_bounds__(256) void conv_silu_kernel(
    const bf16* __restrict__ proj, const float* __restrict__ cw,
    bf16* __restrict__ out) {
  long i = ((long)blockIdx.x * 256 + threadIdx.x) * 4;
  if (i >= (long)ROWS * CONV_DIM) return;
  int ch = (int)(i % CONV_DIM);        // multiple of 4
  long bl = i / CONV_DIM;
  int l = (int)(bl & (SEQ - 1));
  const bf16* p = proj + bl * PROJ_PAD + INTER + ch;
  float a[4] = {0.f, 0.f, 0.f, 0.f};
#pragma unroll
  for (int tap = 0; tap < 4; tap++) {
    int back = 3 - tap;
    if (l >= back) {
      bf16x4 v = *(const bf16x4*)(p - (long)back * PROJ_PAD);
#pragma unroll
      for (int j = 0; j < 4; j++) a[j] += (float)v[j] * cw[(ch + j) * 4 + tap];
    }
  }
  bf16x4 o;
#pragma unroll
  for (int j = 0; j < 4; j++) {
    float s = a[j] / (1.f + expf(-a[j]));
    o[j] = (bf16)s;
  }
  *(bf16x4*)(out + i) = o;
}

// ---------------------------------------------- dt softplus + per-chunk scan
// block = (b*64+h)*8 + c ; 256 threads = chunk positions
__global__ __launch_bounds__(256) void dt_scan_kernel(
    const float* __restrict__ dtraw, const float* __restrict__ dt_bias,
    const float* __restrict__ A_log, float* __restrict__ dtb,
    float* __restrict__ cumA) {
  int idx = blockIdx.x;
  int c = idx & 7, h = (idx >> 3) & 63, b = idx >> 9;
  int s = threadIdx.x;
  long row = (long)b * SEQ + c * CHUNK + s;
  float x = dtraw[row * NUMH + h] + dt_bias[h];
  float dt = (x > 20.f) ? x : log1pf(expf(x));
  dtb[row * NUMH + h] = dt;
  float dA = -expf(A_log[h]) * dt;
  __shared__ float sc[256];
  sc[s] = dA;
  __syncthreads();
  for (int off = 1; off < 256; off <<= 1) {
    float v = (s >= off) ? sc[s - off] : 0.f;
    __syncthreads();
    sc[s] += v;
    __syncthreads();
  }
  cumA[(long)idx * 256 + s] = sc[s];
}

// ------------------------------------------------- G = C @ B^T  (per (b,c))
__global__ __launch_bounds__(256) void g_kernel(
    const bf16* __restrict__ conv, float* __restrict__ G) {
  int bc = blockIdx.x, tt = blockIdx.y, st = blockIdx.z;
  if (st > tt) return;  // upper triangle never read
  int b = bc >> 3, c = bc & 7;
  int tid = threadIdx.x;
  __shared__ float sC[16 * 130];
  __shared__ float sB[16 * 130];
  long rowBase = (long)b * SEQ + c * CHUNK;
  for (int i = tid; i < 16 * 128; i += 256) {
    int r = i >> 7, n = i & 127;
    sC[r * 130 + n] = (float)conv[(rowBase + tt * 16 + r) * CONV_DIM + INTER + STATE + n];
    sB[r * 130 + n] = (float)conv[(rowBase + st * 16 + r) * CONV_DIM + INTER + n];
  }
  __syncthreads();
  int ty = tid >> 4, sx = tid & 15;
  float acc = 0.f;
  for (int n = 0; n < 128; n++) acc += sC[ty * 130 + n] * sB[sx * 130 + n];
  G[((long)bc << 16) + (long)(tt * 16 + ty) * 256 + st * 16 + sx] = acc;
}

// --------------------------------------- per-chunk states S[n][p] (b,c,h)
__global__ __launch_bounds__(256) void states_kernel(
    const bf16* __restrict__ conv, const float* __restrict__ dtb,
    const float* __restrict__ cumA, float* __restrict__ S) {
  int idx = blockIdx.x;  // ((b*8+c)*64+h)
  int h = idx & 63, c = (idx >> 6) & 7, b = idx >> 9;
  int tid = threadIdx.x;
  __shared__ float sB[64 * 128];
  __shared__ float sX[64 * 64];
  float acc[32] = {};
  long caBase = ((long)(b * 64 + h) * 8 + c) * 256;
  float aLast = cumA[caBase + 255];
  long rowBase = (long)b * SEQ + c * CHUNK;
  int tn = (tid & 15) * 8;
  int tp = (tid >> 4) * 4;
  for (int s0 = 0; s0 < 256; s0 += 64) {
    __syncthreads();
    for (int i = tid; i < 64 * 128; i += 256) {
      int sr = i >> 7, n = i & 127;
      sB[i] = (float)conv[(rowBase + s0 + sr) * CONV_DIM + INTER + n];
    }
    for (int i = tid; i < 64 * 64; i += 256) {
      int sr = i >> 6, p = i & 63;
      long row = rowBase + s0 + sr;
      float w = expf(aLast - cumA[caBase + s0 + sr]) * dtb[row * NUMH + h];
      sX[i] = (float)conv[row * CONV_DIM + h * HDIM + p] * w;
    }
    __syncthreads();
    for (int sr = 0; sr < 64; sr++) {
      float bv[8], xv[4];
#pragma unroll
      for (int j = 0; j < 8; j++) bv[j] = sB[sr * 128 + tn + j];
#pragma unroll
      for (int j = 0; j < 4; j++) xv[j] = sX[sr * 64 + tp + j];
#pragma unroll
      for (int n8 = 0; n8 < 8; n8++)
#pragma unroll
        for (int p4 = 0; p4 < 4; p4++)
          acc[n8 * 4 + p4] += bv[n8] * xv[p4];
    }
  }
  float* Sp = S + ((long)idx << 13);
#pragma unroll
  for (int n8 = 0; n8 < 8; n8++)
#pragma unroll
    for (int p4 = 0; p4 < 4; p4++)
      Sp[(tn + n8) * 64 + tp + p4] = acc[n8 * 4 + p4];
}

// ---------------------------------------- inter-chunk recurrence (b,h) block
__global__ __launch_bounds__(256) void recur_kernel(
    const float* __restrict__ S, const float* __restrict__ cumA,
    float* __restrict__ P) {
  int bh = blockIdx.x;
  int b = bh >> 6, h = bh & 63;
  int tid = threadIdx.x;
  float p[32];
#pragma unroll
  for (int k = 0; k < 32; k++) p[k] = 0.f;
  for (int c = 0; c < 8; c++) {
    long blk = ((long)(b * 8 + c) * 64 + h) << 13;
#pragma unroll
    for (int k = 0; k < 32; k++) P[blk + k * 256 + tid] = p[k];
    float e = expf(cumA[((long)bh * 8 + c) * 256 + 255]);
#pragma unroll
    for (int k = 0; k < 32; k++) p[k] = S[blk + k * 256 + tid] + e * p[k];
  }
}

// ------------------------------------------------ Y = diag + off + D*x
__global__ __launch_bounds__(256) void y_kernel(
    const bf16* __restrict__ conv, const float* __restrict__ dtb,
    const float* __restrict__ cumA, const float* __restrict__ G,
    const float* __restrict__ P, const float* __restrict__ D,
    bf16* __restrict__ ybuf) {
  int idx = blockIdx.x;  // ((b*8+c)*64+h)
  int h = idx & 63, c = (idx >> 6) & 7, b = idx >> 9;
  int t = threadIdx.x;
  __shared__ float sP[128 * 64];
  __shared__ float sX[64 * 64];
  __shared__ float scA[256];
  long caBase = ((long)(b * 64 + h) * 8 + c) * 256;
  long rowBase = (long)b * SEQ + c * CHUNK;
  scA[t] = cumA[caBase + t];
  const float* Pblk = P + ((long)idx << 13);
  for (int i = t; i < 8192; i += 256) sP[i] = Pblk[i];
  __syncthreads();
  float cA_t = scA[t];
  floatx4 acc[16] = {};
  const bf16* Crow = conv + (rowBase + t) * CONV_DIM + INTER + STATE;
  for (int n = 0; n < 128; n++) {
    float cv = (float)Crow[n];
    const floatx4* pr = (const floatx4*)&sP[n * 64];
#pragma unroll
    for (int k = 0; k < 16; k++) acc[k] += cv * pr[k];
  }
  float sd = expf(cA_t);
#pragma unroll
  for (int k = 0; k < 16; k++) acc[k] *= sd;
  const float* Grow = G + ((long)(b * 8 + c) << 16) + (long)t * 256;
  for (int s0 = 0; s0 < 256; s0 += 64) {
    __syncthreads();
    for (int i = t; i < 64 * 64; i += 256) {
      int sr = i >> 6, pp = i & 63;
      long row = rowBase + s0 + sr;
      sX[i] = (float)conv[row * CONV_DIM + h * HDIM + pp] * dtb[row * NUMH + h];
    }
    __syncthreads();
    int smax = min(t - s0, 63);
    for (int s = 0; s <= smax; s++) {
      float f = Grow[s0 + s] * expf(cA_t - scA[s0 + s]);
      const floatx4* xr = (const floatx4*)&sX[s * 64];
#pragma unroll
      for (int k = 0; k < 16; k++) acc[k] += f * xr[k];
    }
  }
  float d = D[h];
  bf16* yrow = ybuf + (rowBase + t) * INTER + h * HDIM;
  const bf16* xrow = conv + (rowBase + t) * CONV_DIM + h * HDIM;
#pragma unroll
  for (int k = 0; k < 16; k++)
#pragma unroll
    for (int j = 0; j < 4; j++)
      yrow[k * 4 + j] = (bf16)(acc[k][j] + d * (float)xrow[k * 4 + j]);
}

// ------------------------------------------------------- gated RMSNorm->bf16
__global__ __launch_bounds__(256) void rmsnorm_kernel(
    const bf16* __restrict__ ybuf, const bf16* __restrict__ proj,
    const float* __restrict__ nw, bf16* __restrict__ gb) {
  long row = blockIdx.x;
  int tid = threadIdx.x;
  float gv[16];
  float ss = 0.f;
#pragma unroll
  for (int k = 0; k < 16; k++) {
    int i = k * 256 + tid;
    float y = (float)ybuf[row * INTER + i];
    float gt = (float)proj[row * PROJ_PAD + i];
    float g = y * (gt / (1.f + expf(-gt)));
    gv[k] = g;
    ss += g * g;
  }
#pragma unroll
  for (int off = 32; off > 0; off >>= 1) ss += __shfl_down(ss, off, 64);
  __shared__ float red[4];
  if ((tid & 63) == 0) red[tid >> 6] = ss;
  __syncthreads();
  float tot = red[0] + red[1] + red[2] + red[3];
  float scale = rsqrtf(tot * (1.f / 4096.f) + 1e-5f);
#pragma unroll
  for (int k = 0; k < 16; k++) {
    int i = k * 256 + tid;
    gb[row * INTER + i] = (bf16)(gv[k] * scale * nw[i]);
  }
}

// ============================================================== launch
// Workspace layout (total 198,705,152 B < 199 MB), with lifetime overlays:
//   [0          , 16,777,216 )  hsb bf16      (cvt -> gemm1)      } later S (32MB,
//   [16,777,216 , 51,904,512 )  wb  bf16      (cvt -> gemm1)      }  steps 6-7),
//                                                                  } then ybuf bf16
//                                                                  }  (steps 8-9)
//   [35,127,296 , 51,904,512 )  owb bf16      (cvt after gemm1 -> gemm2)
//   [51,904,512 , 122,159,104)  proj bf16 4096x8576
//   [122,159,104, 157,810,688)  conv bf16 4096x4352
//   [157,810,688, 158,859,264)  dtraw f32 4096x64
//   [158,859,264, 159,907,840)  dtb   f32 4096x64
//   [159,907,840, 160,956,416)  cumA  f32 (b,h,c,256)
//   [160,956,416, 165,150,720)  G     f32 (b,c,256,256)
//   [165,150,720, 198,705,152)  P f32 (steps 7-8), then gb bf16 (steps 9-10)
extern "C" void kernel_launch(void* const* d_in, const int* in_sizes, int n_in,
                              void* d_out, int out_size, void* d_ws, size_t ws_size,
                              hipStream_t stream) {
  const float* hs   = (const float*)d_in[0];
  const float* ipw  = (const float*)d_in[1];
  const float* ipb  = (const float*)d_in[2];
  const float* cw   = (const float*)d_in[3];
  const float* dtbi = (const float*)d_in[4];
  const float* alog = (const float*)d_in[5];
  const float* Dp   = (const float*)d_in[6];
  const float* nw   = (const float*)d_in[7];
  const float* opw  = (const float*)d_in[8];
  const float* opb  = (const float*)d_in[9];
  float* out = (float*)d_out;

  char* ws = (char*)d_ws;
  bf16*  hsb   = (bf16*)(ws + 0);
  bf16*  wb    = (bf16*)(ws + 16777216);
  float* S     = (float*)(ws + 0);           // overlays hsb+wb (dead after gemm1)
  bf16*  ybuf  = (bf16*)(ws + 0);            // overlays S (dead after recur)
  bf16*  owb   = (bf16*)(ws + 35127296);     // overlays upper wb (dead after gemm1)
  bf16*  proj  = (bf16*)(ws + 51904512);
  bf16*  conv  = (bf16*)(ws + 122159104);
  float* dtraw = (float*)(ws + 157810688);
  float* dtb   = (float*)(ws + 158859264);
  float* cumA  = (float*)(ws + 159907840);
  float* G     = (float*)(ws + 160956416);
  float* P     = (float*)(ws + 165150720);
  bf16*  gb    = (bf16*)(ws + 165150720);    // overlays P (dead after y_kernel)

  // input conversions needed before gemm1
  cvt_bf16_kernel<<<8192, 256, 0, stream>>>(hs, hsb, (long)ROWS * HIDDEN, (long)ROWS * HIDDEN);
  cvt_bf16_kernel<<<17152, 256, 0, stream>>>(ipw, wb, (long)PROJ_PAD * HIDDEN, (long)PROJ_N * HIDDEN);

  // in_proj GEMM: (4096 x 2048) @ (8576 x 2048)^T -> proj bf16 (+ dtraw f32)
  gemm_bt_kernel<<<dim3(PROJ_PAD / 128, ROWS / 128), 256, 0, stream>>>(
      hsb, wb, ipb, proj, nullptr, dtraw, ROWS, PROJ_PAD, HIDDEN, PROJ_N, DT_COL0);

  // out_proj weight conversion (into region freed by wb)
  cvt_bf16_kernel<<<8192, 256, 0, stream>>>(opw, owb, (long)HIDDEN * INTER, (long)HIDDEN * INTER);

  // conv + silu (bf16 in/out)
  conv_silu_kernel<<<17408, 256, 0, stream>>>(proj, cw, conv);

  // dt softplus + per-chunk cumsum (f32 dtraw side-channel)
  dt_scan_kernel<<<1024, 256, 0, stream>>>(dtraw, dtbi, alog, dtb, cumA);

  // G = C B^T per (b,c), lower triangle only
  g_kernel<<<dim3(16, 16, 16), 256, 0, stream>>>(conv, G);

  // per-chunk states (into region freed by hsb/wb)
  states_kernel<<<1024, 256, 0, stream>>>(conv, dtb, cumA, S);

  // inter-chunk recurrence
  recur_kernel<<<128, 256, 0, stream>>>(S, cumA, P);

  // Y (diag + off + skip) -> ybuf bf16 (overlays S)
  y_kernel<<<1024, 256, 0, stream>>>(conv, dtb, cumA, G, P, Dp, ybuf);

  // gated RMSNorm -> gb bf16 (overlays P)
  rmsnorm_kernel<<<4096, 256, 0, stream>>>(ybuf, proj, nw, gb);

  // out_proj GEMM: (4096 x 4096) @ (2048 x 4096)^T -> out f32
  gemm_bt_kernel<<<dim3(HIDDEN / 128, ROWS / 128), 256, 0, stream>>>(
      gb, owb, opb, nullptr, out, nullptr, ROWS, HIDDEN, INTER, HIDDEN, 1 << 30);
}

// Round 3
// 813.545 us; speedup vs baseline: 1.4287x; 1.4287x over previous
//
#include <hip/hip_runtime.h>

typedef __bf16 bf16;
typedef __bf16 bf16x8 __attribute__((ext_vector_type(8)));
typedef __bf16 bf16x4 __attribute__((ext_vector_type(4)));
typedef float  floatx4 __attribute__((ext_vector_type(4)));

#define HIDDEN   2048
#define NUMH     64
#define HDIM     64
#define STATE    128
#define INTER    4096
#define CONV_DIM 4352
#define PROJ_N   8512
#define PROJ_PAD 8576
#define SEQ      2048
#define BATCH    2
#define CHUNK    256
#define NCHUNK   8
#define ROWS     4096   // BATCH*SEQ
#define DT_COL0  8448   // INTER + CONV_DIM

// async global->LDS, 16B per lane, LDS dest = wave-uniform base + lane*16
#define GLDS(gp, lp) __builtin_amdgcn_global_load_lds(                      \
    (const __attribute__((address_space(1))) void*)(gp),                    \
    (__attribute__((address_space(3))) void*)(lp), 16, 0, 0)

// ---------------------------------------------------------------- f32 -> bf16
__global__ __launch_bounds__(256) void cvt_bf16_kernel(
    const float* __restrict__ in, bf16* __restrict__ out, long n, long srcn) {
  long i = ((long)blockIdx.x * 256 + threadIdx.x) * 4;
  if (i >= n) return;
  if (i + 3 < srcn) {
    const float* p = in + i;
    bf16x4 o;
    o[0] = (bf16)p[0]; o[1] = (bf16)p[1]; o[2] = (bf16)p[2]; o[3] = (bf16)p[3];
    *(bf16x4*)(out + i) = o;
  } else {
    for (int j = 0; j < 4; j++) {
      float v = (i + j < srcn) ? in[i + j] : 0.f;
      out[i + j] = (bf16)v;
    }
  }
}

// ------------------------------------------------------- bf16 MFMA GEMM (BT)
// C[M][N] = A[M][K] @ B[N][K]^T + bias ; m97 structure (global_load_lds w=16)
__global__ __launch_bounds__(256, 2) void gemm_bt_kernel(
    const bf16* __restrict__ A, const bf16* __restrict__ B,
    const float* __restrict__ bias, bf16* __restrict__ Cb,
    float* __restrict__ Cf, float* __restrict__ ds,
    int M, int N, int K, int bias_n, int dt0) {
  __shared__ __align__(16) bf16 lA[128 * 32];
  __shared__ __align__(16) bf16 lB[128 * 32];
  const int tid  = threadIdx.x;
  const int lane = tid & 63;
  const int wave = tid >> 6;
  const int m0 = blockIdx.y * 128;
  const int n0 = blockIdx.x * 128;
  const int wm = (wave >> 1) * 64;
  const int wn = (wave & 1) * 64;
  const int q  = lane >> 4;     // 0..3
  const int ln = lane & 15;
  const int r0 = tid >> 2;      // 0..63
  const int c0 = (tid & 3) * 8; // 0,8,16,24

  floatx4 acc[4][4] = {};

  const bf16* Ap = A + (long)(m0 + r0) * K + c0;
  const bf16* Bp = B + (long)(n0 + r0) * K + c0;
  bf16* lAw = lA + wave * 512;   // wave-uniform LDS base (lane*16B appended by HW)
  bf16* lBw = lB + wave * 512;

  for (int k0 = 0; k0 < K; k0 += 32) {
    __syncthreads();
    GLDS(Ap + k0, lAw);
    GLDS(Ap + (long)64 * K + k0, lAw + 2048);
    GLDS(Bp + k0, lBw);
    GLDS(Bp + (long)64 * K + k0, lBw + 2048);
    __syncthreads();
    bf16x8 af[4], bg[4];
#pragma unroll
    for (int i = 0; i < 4; i++) {
      af[i] = *(const bf16x8*)(lA + (wm + i * 16 + ln) * 32 + q * 8);
      bg[i] = *(const bf16x8*)(lB + (wn + i * 16 + ln) * 32 + q * 8);
    }
#pragma unroll
    for (int mi = 0; mi < 4; mi++)
#pragma unroll
      for (int ni = 0; ni < 4; ni++)
        acc[mi][ni] = __builtin_amdgcn_mfma_f32_16x16x32_bf16(
            af[mi], bg[ni], acc[mi][ni], 0, 0, 0);
  }

#pragma unroll
  for (int mi = 0; mi < 4; mi++) {
#pragma unroll
    for (int ni = 0; ni < 4; ni++) {
      int col = n0 + wn + ni * 16 + ln;
      float bv = (col < bias_n) ? bias[col] : 0.f;
#pragma unroll
      for (int r = 0; r < 4; r++) {
        int row = m0 + wm + mi * 16 + q * 4 + r;
        float v = acc[mi][ni][r] + bv;
        if (Cb) Cb[(long)row * N + col] = (bf16)v;
        else    Cf[(long)row * N + col] = v;
        if (ds && col >= dt0 && col < dt0 + 64)
          ds[(long)row * 64 + (col - dt0)] = v;
      }
    }
  }
}

// ------------------------------------------------------- causal conv4 + SiLU
__global__ __launch_bounds__(256) void conv_silu_kernel(
    const bf16* __restrict__ proj, const float* __restrict__ cw,
    bf16* __restrict__ out) {
  long i = ((long)blockIdx.x * 256 + threadIdx.x) * 4;
  if (i >= (long)ROWS * CONV_DIM) return;
  int ch = (int)(i % CONV_DIM);        // multiple of 4
  long bl = i / CONV_DIM;
  int l = (int)(bl & (SEQ - 1));
  const bf16* p = proj + bl * PROJ_PAD + INTER + ch;
  float a[4] = {0.f, 0.f, 0.f, 0.f};
#pragma unroll
  for (int tap = 0; tap < 4; tap++) {
    int back = 3 - tap;
    if (l >= back) {
      bf16x4 v = *(const bf16x4*)(p - (long)back * PROJ_PAD);
#pragma unroll
      for (int j = 0; j < 4; j++) a[j] += (float)v[j] * cw[(ch + j) * 4 + tap];
    }
  }
  bf16x4 o;
#pragma unroll
  for (int j = 0; j < 4; j++) {
    float s = a[j] / (1.f + expf(-a[j]));
    o[j] = (bf16)s;
  }
  *(bf16x4*)(out + i) = o;
}

// ---------------------------------------------- dt softplus + per-chunk scan
__global__ __launch_bounds__(256) void dt_scan_kernel(
    const float* __restrict__ dtraw, const float* __restrict__ dt_bias,
    const float* __restrict__ A_log, float* __restrict__ dtb,
    float* __restrict__ cumA) {
  int idx = blockIdx.x;
  int c = idx & 7, h = (idx >> 3) & 63, b = idx >> 9;
  int s = threadIdx.x;
  long row = (long)b * SEQ + c * CHUNK + s;
  float x = dtraw[row * NUMH + h] + dt_bias[h];
  float dt = (x > 20.f) ? x : log1pf(expf(x));
  dtb[row * NUMH + h] = dt;
  float dA = -expf(A_log[h]) * dt;
  __shared__ float sc[256];
  sc[s] = dA;
  __syncthreads();
  for (int off = 1; off < 256; off <<= 1) {
    float v = (s >= off) ? sc[s - off] : 0.f;
    __syncthreads();
    sc[s] += v;
    __syncthreads();
  }
  cumA[(long)idx * 256 + s] = sc[s];
}

// ------------------------------------------------- G = C @ B^T  (per (b,c))
__global__ __launch_bounds__(256) void g_kernel(
    const bf16* __restrict__ conv, float* __restrict__ G) {
  int bc = blockIdx.x, tt = blockIdx.y, st = blockIdx.z;
  if (st > tt) return;  // upper triangle never read
  int b = bc >> 3, c = bc & 7;
  int tid = threadIdx.x;
  __shared__ float sC[16 * 130];
  __shared__ float sB[16 * 130];
  long rowBase = (long)b * SEQ + c * CHUNK;
  for (int i = tid; i < 16 * 128; i += 256) {
    int r = i >> 7, n = i & 127;
    sC[r * 130 + n] = (float)conv[(rowBase + tt * 16 + r) * CONV_DIM + INTER + STATE + n];
    sB[r * 130 + n] = (float)conv[(rowBase + st * 16 + r) * CONV_DIM + INTER + n];
  }
  __syncthreads();
  int ty = tid >> 4, sx = tid & 15;
  float acc = 0.f;
  for (int n = 0; n < 128; n++) acc += sC[ty * 130 + n] * sB[sx * 130 + n];
  G[((long)bc << 16) + (long)(tt * 16 + ty) * 256 + st * 16 + sx] = acc;
}

// --------------------------------------- per-chunk states S[n][p] (b,c,h)
__global__ __launch_bounds__(256) void states_kernel(
    const bf16* __restrict__ conv, const float* __restrict__ dtb,
    const float* __restrict__ cumA, float* __restrict__ S) {
  int idx = blockIdx.x;  // ((b*8+c)*64+h)
  int h = idx & 63, c = (idx >> 6) & 7, b = idx >> 9;
  int tid = threadIdx.x;
  __shared__ float sB[64 * 128];
  __shared__ float sX[64 * 64];
  float acc[32] = {};
  long caBase = ((long)(b * 64 + h) * 8 + c) * 256;
  float aLast = cumA[caBase + 255];
  long rowBase = (long)b * SEQ + c * CHUNK;
  int tn = (tid & 15) * 8;
  int tp = (tid >> 4) * 4;
  for (int s0 = 0; s0 < 256; s0 += 64) {
    __syncthreads();
    for (int i = tid; i < 64 * 128; i += 256) {
      int sr = i >> 7, n = i & 127;
      sB[i] = (float)conv[(rowBase + s0 + sr) * CONV_DIM + INTER + n];
    }
    for (int i = tid; i < 64 * 64; i += 256) {
      int sr = i >> 6, p = i & 63;
      long row = rowBase + s0 + sr;
      float w = expf(aLast - cumA[caBase + s0 + sr]) * dtb[row * NUMH + h];
      sX[i] = (float)conv[row * CONV_DIM + h * HDIM + p] * w;
    }
    __syncthreads();
    for (int sr = 0; sr < 64; sr++) {
      float bv[8], xv[4];
#pragma unroll
      for (int j = 0; j < 8; j++) bv[j] = sB[sr * 128 + tn + j];
#pragma unroll
      for (int j = 0; j < 4; j++) xv[j] = sX[sr * 64 + tp + j];
#pragma unroll
      for (int n8 = 0; n8 < 8; n8++)
#pragma unroll
        for (int p4 = 0; p4 < 4; p4++)
          acc[n8 * 4 + p4] += bv[n8] * xv[p4];
    }
  }
  float* Sp = S + ((long)idx << 13);
#pragma unroll
  for (int n8 = 0; n8 < 8; n8++)
#pragma unroll
    for (int p4 = 0; p4 < 4; p4++)
      Sp[(tn + n8) * 64 + tp + p4] = acc[n8 * 4 + p4];
}

// ---------------------------------------- inter-chunk recurrence (b,h) block
__global__ __launch_bounds__(256) void recur_kernel(
    const float* __restrict__ S, const float* __restrict__ cumA,
    float* __restrict__ P) {
  int bh = blockIdx.x;
  int b = bh >> 6, h = bh & 63;
  int tid = threadIdx.x;
  float p[32];
#pragma unroll
  for (int k = 0; k < 32; k++) p[k] = 0.f;
  for (int c = 0; c < 8; c++) {
    long blk = ((long)(b * 8 + c) * 64 + h) << 13;
#pragma unroll
    for (int k = 0; k < 32; k++) P[blk + k * 256 + tid] = p[k];
    float e = expf(cumA[((long)bh * 8 + c) * 256 + 255]);
#pragma unroll
    for (int k = 0; k < 32; k++) p[k] = S[blk + k * 256 + tid] + e * p[k];
  }
}

// ------------------------------------------------ Y = diag + off + D*x (MFMA)
// block = (b,c,h); wave w owns t rows [64w, 64w+64)
__global__ __launch_bounds__(256, 2) void y_kernel(
    const bf16* __restrict__ conv, const float* __restrict__ dtb,
    const float* __restrict__ cumA, const float* __restrict__ G,
    const float* __restrict__ P, const float* __restrict__ D,
    bf16* __restrict__ ybuf) {
  int idx = blockIdx.x;  // ((b*8+c)*64+h)
  int h = idx & 63, c = (idx >> 6) & 7, b = idx >> 9;
  int tid = threadIdx.x, lane = tid & 63, w = tid >> 6;
  int q = lane >> 4, ln = lane & 15;
  // k-chunked LDS layouts (conflict-free b128 frag reads, gemm lB-style)
  __shared__ __align__(16) bf16 sPT[128 * 64];   // ((n>>5)*64+p)*32+(n&31)
  __shared__ __align__(16) bf16 sXT[256 * 64];   // ((s>>5)*64+p)*32+(s&31)
  __shared__ float scA[256];
  long caBase = ((long)(b * 64 + h) * 8 + c) * 256;
  long rowBase = (long)b * SEQ + c * CHUNK;
  const float* Gbase = G + ((long)(b * 8 + c) << 16);

  scA[tid] = cumA[caBase + tid];
  // stage P^T (f32 [n][p] -> bf16 k-chunked)
  {
    const float* Pblk = P + ((long)idx << 13);
    int n = tid >> 1;
    int p0 = (tid & 1) * 32;
    int nc = (n >> 5) * 64, nk = n & 31;
#pragma unroll
    for (int pp = 0; pp < 32; pp += 4) {
      floatx4 v = *(const floatx4*)(Pblk + n * 64 + p0 + pp);
#pragma unroll
      for (int j = 0; j < 4; j++)
        sPT[(nc + p0 + pp + j) * 32 + nk] = (bf16)v[j];
    }
  }
  // stage X^T (x * dt, bf16 k-chunked); thread = one s
  {
    int s = tid;
    long row = rowBase + s;
    float dt = dtb[row * NUMH + h];
    int sc = (s >> 5) * 64, sk = s & 31;
    const bf16* xr = conv + row * CONV_DIM + h * HDIM;
#pragma unroll
    for (int p0 = 0; p0 < 64; p0 += 8) {
      bf16x8 xv = *(const bf16x8*)(xr + p0);
#pragma unroll
      for (int j = 0; j < 8; j++)
        sXT[(sc + p0 + j) * 32 + sk] = (bf16)((float)xv[j] * dt);
    }
  }
  __syncthreads();

  floatx4 acc[4][4] = {};

  // ---- phase 1: Y_off = C @ P^T  (A-frags straight from global)
  const bf16* Cbase = conv + (rowBase + w * 64) * CONV_DIM + INTER + STATE;
  for (int k0 = 0; k0 < 128; k0 += 32) {
    bf16x8 af[4], bg[4];
#pragma unroll
    for (int mi = 0; mi < 4; mi++)
      af[mi] = *(const bf16x8*)(Cbase + (long)(mi * 16 + ln) * CONV_DIM + k0 + q * 8);
#pragma unroll
    for (int ni = 0; ni < 4; ni++)
      bg[ni] = *(const bf16x8*)(sPT + ((k0 >> 5) * 64 + ni * 16 + ln) * 32 + q * 8);
#pragma unroll
    for (int mi = 0; mi < 4; mi++)
#pragma unroll
      for (int ni = 0; ni < 4; ni++)
        acc[mi][ni] = __builtin_amdgcn_mfma_f32_16x16x32_bf16(
            af[mi], bg[ni], acc[mi][ni], 0, 0, 0);
  }
  // row decay exp(cA_t)
#pragma unroll
  for (int mi = 0; mi < 4; mi++)
#pragma unroll
    for (int r = 0; r < 4; r++) {
      float e = __expf(scA[w * 64 + mi * 16 + q * 4 + r]);
#pragma unroll
      for (int ni = 0; ni < 4; ni++) acc[mi][ni][r] *= e;
    }

  // ---- phase 2: Y_diag = M @ X, M[t][s] = s<=t ? G*exp(cA_t-cA_s) : 0
  for (int sb = 0; sb <= w; sb++) {
#pragma unroll
    for (int kk = 0; kk < 64; kk += 32) {
      int s0 = sb * 64 + kk;
      bf16x8 af[4], bg[4];
#pragma unroll
      for (int mi = 0; mi < 4; mi++) {
        int t = w * 64 + mi * 16 + ln;
        float cAt = scA[t];
        const float* Gr = Gbase + (long)t * 256 + s0 + q * 8;
        floatx4 g0 = *(const floatx4*)Gr;
        floatx4 g1 = *(const floatx4*)(Gr + 4);
        bf16x8 m;
#pragma unroll
        for (int j = 0; j < 4; j++) {
          int s = s0 + q * 8 + j;
          float v = g0[j] * __expf(cAt - scA[s]);
          m[j] = (bf16)((s <= t) ? v : 0.f);
        }
#pragma unroll
        for (int j = 4; j < 8; j++) {
          int s = s0 + q * 8 + j;
          float v = g1[j - 4] * __expf(cAt - scA[s]);
          m[j] = (bf16)((s <= t) ? v : 0.f);
        }
        af[mi] = m;
      }
#pragma unroll
      for (int ni = 0; ni < 4; ni++)
        bg[ni] = *(const bf16x8*)(sXT + ((s0 >> 5) * 64 + ni * 16 + ln) * 32 + q * 8);
#pragma unroll
      for (int mi = 0; mi < 4; mi++)
#pragma unroll
        for (int ni = 0; ni < 4; ni++)
          acc[mi][ni] = __builtin_amdgcn_mfma_f32_16x16x32_bf16(
              af[mi], bg[ni], acc[mi][ni], 0, 0, 0);
    }
  }

  // ---- epilogue: + D*x, store bf16
  float d = D[h];
#pragma unroll
  for (int mi = 0; mi < 4; mi++)
#pragma unroll
    for (int ni = 0; ni < 4; ni++) {
      int col = ni * 16 + ln;
#pragma unroll
      for (int r = 0; r < 4; r++) {
        long row = rowBase + w * 64 + mi * 16 + q * 4 + r;
        float xv = (float)conv[row * CONV_DIM + h * HDIM + col];
        ybuf[row * INTER + h * HDIM + col] = (bf16)(acc[mi][ni][r] + d * xv);
      }
    }
}

// ------------------------------------------------------- gated RMSNorm->bf16
__global__ __launch_bounds__(256) void rmsnorm_kernel(
    const bf16* __restrict__ ybuf, const bf16* __restrict__ proj,
    const float* __restrict__ nw, bf16* __restrict__ gb) {
  long row = blockIdx.x;
  int tid = threadIdx.x;
  float gv[16];
  float ss = 0.f;
#pragma unroll
  for (int k = 0; k < 16; k++) {
    int i = k * 256 + tid;
    float y = (float)ybuf[row * INTER + i];
    float gt = (float)proj[row * PROJ_PAD + i];
    float g = y * (gt / (1.f + expf(-gt)));
    gv[k] = g;
    ss += g * g;
  }
#pragma unroll
  for (int off = 32; off > 0; off >>= 1) ss += __shfl_down(ss, off, 64);
  __shared__ float red[4];
  if ((tid & 63) == 0) red[tid >> 6] = ss;
  __syncthreads();
  float tot = red[0] + red[1] + red[2] + red[3];
  float scale = rsqrtf(tot * (1.f / 4096.f) + 1e-5f);
#pragma unroll
  for (int k = 0; k < 16; k++) {
    int i = k * 256 + tid;
    gb[row * INTER + i] = (bf16)(gv[k] * scale * nw[i]);
  }
}

// ============================================================== launch
// Workspace layout (total 198,705,152 B), lifetime overlays as round 1.
extern "C" void kernel_launch(void* const* d_in, const int* in_sizes, int n_in,
                              void* d_out, int out_size, void* d_ws, size_t ws_size,
                              hipStream_t stream) {
  const float* hs   = (const float*)d_in[0];
  const float* ipw  = (const float*)d_in[1];
  const float* ipb  = (const float*)d_in[2];
  const float* cw   = (const float*)d_in[3];
  const float* dtbi = (const float*)d_in[4];
  const float* alog = (const float*)d_in[5];
  const float* Dp   = (const float*)d_in[6];
  const float* nw   = (const float*)d_in[7];
  const float* opw  = (const float*)d_in[8];
  const float* opb  = (const float*)d_in[9];
  float* out = (float*)d_out;

  char* ws = (char*)d_ws;
  bf16*  hsb   = (bf16*)(ws + 0);
  bf16*  wb    = (bf16*)(ws + 16777216);
  float* S     = (float*)(ws + 0);           // overlays hsb+wb (dead after gemm1)
  bf16*  ybuf  = (bf16*)(ws + 0);            // overlays S (dead after recur)
  bf16*  owb   = (bf16*)(ws + 35127296);     // overlays upper wb (dead after gemm1)
  bf16*  proj  = (bf16*)(ws + 51904512);
  bf16*  conv  = (bf16*)(ws + 122159104);
  float* dtraw = (float*)(ws + 157810688);
  float* dtb   = (float*)(ws + 158859264);
  float* cumA  = (float*)(ws + 159907840);
  float* G     = (float*)(ws + 160956416);
  float* P     = (float*)(ws + 165150720);
  bf16*  gb    = (bf16*)(ws + 165150720);    // overlays P (dead after y_kernel)

  cvt_bf16_kernel<<<8192, 256, 0, stream>>>(hs, hsb, (long)ROWS * HIDDEN, (long)ROWS * HIDDEN);
  cvt_bf16_kernel<<<17152, 256, 0, stream>>>(ipw, wb, (long)PROJ_PAD * HIDDEN, (long)PROJ_N * HIDDEN);

  gemm_bt_kernel<<<dim3(PROJ_PAD / 128, ROWS / 128), 256, 0, stream>>>(
      hsb, wb, ipb, proj, nullptr, dtraw, ROWS, PROJ_PAD, HIDDEN, PROJ_N, DT_COL0);

  cvt_bf16_kernel<<<8192, 256, 0, stream>>>(opw, owb, (long)HIDDEN * INTER, (long)HIDDEN * INTER);

  conv_silu_kernel<<<17408, 256, 0, stream>>>(proj, cw, conv);

  dt_scan_kernel<<<1024, 256, 0, stream>>>(dtraw, dtbi, alog, dtb, cumA);

  g_kernel<<<dim3(16, 16, 16), 256, 0, stream>>>(conv, G);

  states_kernel<<<1024, 256, 0, stream>>>(conv, dtb, cumA, S);

  recur_kernel<<<128, 256, 0, stream>>>(S, cumA, P);

  y_kernel<<<1024, 256, 0, stream>>>(conv, dtb, cumA, G, P, Dp, ybuf);

  rmsnorm_kernel<<<4096, 256, 0, stream>>>(ybuf, proj, nw, gb);

  gemm_bt_kernel<<<dim3(HIDDEN / 128, ROWS / 128), 256, 0, stream>>>(
      gb, owb, opb, nullptr, out, nullptr, ROWS, HIDDEN, INTER, HIDDEN, 1 << 30);
}

// Round 4
// 720.850 us; speedup vs baseline: 1.6125x; 1.1286x over previous
//
#include <hip/hip_runtime.h>

typedef __bf16 bf16;
typedef __bf16 bf16x8 __attribute__((ext_vector_type(8)));
typedef __bf16 bf16x4 __attribute__((ext_vector_type(4)));
typedef float  floatx4 __attribute__((ext_vector_type(4)));

#define HIDDEN   2048
#define NUMH     64
#define HDIM     64
#define STATE    128
#define INTER    4096
#define CONV_DIM 4352
#define PROJ_N   8512
#define PROJ_PAD 8576
#define SEQ      2048
#define BATCH    2
#define CHUNK    256
#define NCHUNK   8
#define ROWS     4096   // BATCH*SEQ
#define DT_COL0  8448   // INTER + CONV_DIM

// async global->LDS, 16B per lane, LDS dest = wave-uniform base + lane*16
#define GLDS(gp, lp) __builtin_amdgcn_global_load_lds(                      \
    (const __attribute__((address_space(1))) void*)(gp),                    \
    (__attribute__((address_space(3))) void*)(lp), 16, 0, 0)

// ---------------------------------------------------------------- f32 -> bf16
__global__ __launch_bounds__(256) void cvt_bf16_kernel(
    const float* __restrict__ in, bf16* __restrict__ out, long n, long srcn) {
  long i = ((long)blockIdx.x * 256 + threadIdx.x) * 4;
  if (i >= n) return;
  if (i + 3 < srcn) {
    const float* p = in + i;
    bf16x4 o;
    o[0] = (bf16)p[0]; o[1] = (bf16)p[1]; o[2] = (bf16)p[2]; o[3] = (bf16)p[3];
    *(bf16x4*)(out + i) = o;
  } else {
    for (int j = 0; j < 4; j++) {
      float v = (i + j < srcn) ? in[i + j] : 0.f;
      out[i + j] = (bf16)v;
    }
  }
}

// ------------------------------------------------------- bf16 MFMA GEMM (BT)
// C[M][N] = A[M][K] @ B[N][K]^T + bias ; m97 structure, XCD-striped raster:
// id%8 -> XCD (dispatch heuristic); each XCD owns a 4-m-tile stripe (2MB of A
// resident in its 4MB L2), streams B n-major. gm must be %8.
__global__ __launch_bounds__(256, 2) void gemm_bt_kernel(
    const bf16* __restrict__ A, const bf16* __restrict__ B,
    const float* __restrict__ bias, bf16* __restrict__ Cb,
    float* __restrict__ Cf, float* __restrict__ ds,
    int M, int N, int K, int bias_n, int dt0) {
  __shared__ __align__(16) bf16 lA[128 * 32];
  __shared__ __align__(16) bf16 lB[128 * 32];
  const int tid  = threadIdx.x;
  const int lane = tid & 63;
  const int wave = tid >> 6;
  const int gm = M >> 7;
  const int id = blockIdx.x;
  const int xcd = id & 7;
  const int j = id >> 3;
  const int mstripe = gm >> 3;
  const int mb = xcd * mstripe + (j % mstripe);
  const int nb = j / mstripe;
  const int m0 = mb * 128;
  const int n0 = nb * 128;
  const int wm = (wave >> 1) * 64;
  const int wn = (wave & 1) * 64;
  const int q  = lane >> 4;     // 0..3
  const int ln = lane & 15;
  const int r0 = tid >> 2;      // 0..63
  const int c0 = (tid & 3) * 8; // 0,8,16,24

  floatx4 acc[4][4] = {};

  const bf16* Ap = A + (long)(m0 + r0) * K + c0;
  const bf16* Bp = B + (long)(n0 + r0) * K + c0;
  bf16* lAw = lA + wave * 512;   // wave-uniform LDS base (lane*16B appended by HW)
  bf16* lBw = lB + wave * 512;

  for (int k0 = 0; k0 < K; k0 += 32) {
    __syncthreads();
    GLDS(Ap + k0, lAw);
    GLDS(Ap + (long)64 * K + k0, lAw + 2048);
    GLDS(Bp + k0, lBw);
    GLDS(Bp + (long)64 * K + k0, lBw + 2048);
    __syncthreads();
    bf16x8 af[4], bg[4];
#pragma unroll
    for (int i = 0; i < 4; i++) {
      af[i] = *(const bf16x8*)(lA + (wm + i * 16 + ln) * 32 + q * 8);
      bg[i] = *(const bf16x8*)(lB + (wn + i * 16 + ln) * 32 + q * 8);
    }
#pragma unroll
    for (int mi = 0; mi < 4; mi++)
#pragma unroll
      for (int ni = 0; ni < 4; ni++)
        acc[mi][ni] = __builtin_amdgcn_mfma_f32_16x16x32_bf16(
            af[mi], bg[ni], acc[mi][ni], 0, 0, 0);
  }

#pragma unroll
  for (int mi = 0; mi < 4; mi++) {
#pragma unroll
    for (int ni = 0; ni < 4; ni++) {
      int col = n0 + wn + ni * 16 + ln;
      float bv = (col < bias_n) ? bias[col] : 0.f;
#pragma unroll
      for (int r = 0; r < 4; r++) {
        int row = m0 + wm + mi * 16 + q * 4 + r;
        float v = acc[mi][ni][r] + bv;
        if (Cb) Cb[(long)row * N + col] = (bf16)v;
        else    Cf[(long)row * N + col] = v;
        if (ds && col >= dt0 && col < dt0 + 64)
          ds[(long)row * 64 + (col - dt0)] = v;
      }
    }
  }
}

// ------------------------------------------------------- causal conv4 + SiLU
__global__ __launch_bounds__(256) void conv_silu_kernel(
    const bf16* __restrict__ proj, const float* __restrict__ cw,
    bf16* __restrict__ out) {
  long i = ((long)blockIdx.x * 256 + threadIdx.x) * 4;
  if (i >= (long)ROWS * CONV_DIM) return;
  int ch = (int)(i % CONV_DIM);        // multiple of 4
  long bl = i / CONV_DIM;
  int l = (int)(bl & (SEQ - 1));
  const bf16* p = proj + bl * PROJ_PAD + INTER + ch;
  float a[4] = {0.f, 0.f, 0.f, 0.f};
#pragma unroll
  for (int tap = 0; tap < 4; tap++) {
    int back = 3 - tap;
    if (l >= back) {
      bf16x4 v = *(const bf16x4*)(p - (long)back * PROJ_PAD);
#pragma unroll
      for (int j = 0; j < 4; j++) a[j] += (float)v[j] * cw[(ch + j) * 4 + tap];
    }
  }
  bf16x4 o;
#pragma unroll
  for (int j = 0; j < 4; j++) {
    float s = a[j] / (1.f + expf(-a[j]));
    o[j] = (bf16)s;
  }
  *(bf16x4*)(out + i) = o;
}

// ---------------------------------------------- dt softplus + per-chunk scan
__global__ __launch_bounds__(256) void dt_scan_kernel(
    const float* __restrict__ dtraw, const float* __restrict__ dt_bias,
    const float* __restrict__ A_log, float* __restrict__ dtb,
    float* __restrict__ cumA) {
  int idx = blockIdx.x;
  int c = idx & 7, h = (idx >> 3) & 63, b = idx >> 9;
  int s = threadIdx.x;
  long row = (long)b * SEQ + c * CHUNK + s;
  float x = dtraw[row * NUMH + h] + dt_bias[h];
  float dt = (x > 20.f) ? x : log1pf(expf(x));
  dtb[row * NUMH + h] = dt;
  float dA = -expf(A_log[h]) * dt;
  __shared__ float sc[256];
  sc[s] = dA;
  __syncthreads();
  for (int off = 1; off < 256; off <<= 1) {
    float v = (s >= off) ? sc[s - off] : 0.f;
    __syncthreads();
    sc[s] += v;
    __syncthreads();
  }
  cumA[(long)idx * 256 + s] = sc[s];
}

// ------------------------------------------------- G = C @ B^T  (MFMA)
// grid (bc, tt, sb); block computes G[64tt..+64][64sb..+64], K=128
__global__ __launch_bounds__(256, 2) void g_kernel(
    const bf16* __restrict__ conv, float* __restrict__ G) {
  int bc = blockIdx.x, tt = blockIdx.y, sb = blockIdx.z;
  if (sb > tt) return;  // upper triangle never read
  int b = bc >> 3, c = bc & 7;
  int tid = threadIdx.x, lane = tid & 63, w = tid >> 6;
  int q = lane >> 4, ln = lane & 15;
  __shared__ __align__(16) bf16 sCg[4 * 64 * 32];  // [(kc*64+t)*32 + (n&31)]
  __shared__ __align__(16) bf16 sBg[4 * 64 * 32];
  long rowBase = (long)b * SEQ + c * CHUNK;
  for (int i = tid; i < 1024; i += 256) {
    int r = i >> 4, n0 = (i & 15) * 8;
    int base = ((n0 >> 5) * 64 + r) * 32 + (n0 & 31);
    bf16x8 cv = *(const bf16x8*)(conv + (rowBase + tt * 64 + r) * CONV_DIM + INTER + STATE + n0);
    *(bf16x8*)(sCg + base) = cv;
    bf16x8 bv = *(const bf16x8*)(conv + (rowBase + sb * 64 + r) * CONV_DIM + INTER + n0);
    *(bf16x8*)(sBg + base) = bv;
  }
  __syncthreads();
  floatx4 acc[4] = {};
#pragma unroll
  for (int kc = 0; kc < 4; kc++) {
    bf16x8 af = *(const bf16x8*)(sCg + (kc * 64 + w * 16 + ln) * 32 + q * 8);
#pragma unroll
    for (int ni = 0; ni < 4; ni++) {
      bf16x8 bg = *(const bf16x8*)(sBg + (kc * 64 + ni * 16 + ln) * 32 + q * 8);
      acc[ni] = __builtin_amdgcn_mfma_f32_16x16x32_bf16(af, bg, acc[ni], 0, 0, 0);
    }
  }
  float* Gb = G + ((long)bc << 16);
#pragma unroll
  for (int ni = 0; ni < 4; ni++) {
    int s = sb * 64 + ni * 16 + ln;
#pragma unroll
    for (int r = 0; r < 4; r++) {
      int t = tt * 64 + w * 16 + q * 4 + r;
      Gb[(long)t * 256 + s] = acc[ni][r];
    }
  }
}

// --------------------------------------- per-chunk states S = B^T·(x·w) MFMA
// block (b,c,h): M=128(n) × N=64(p) × K=256(s); s-chunks of 64
__global__ __launch_bounds__(256, 2) void states_kernel(
    const bf16* __restrict__ conv, const float* __restrict__ dtb,
    const float* __restrict__ cumA, float* __restrict__ S) {
  int idx = blockIdx.x;  // ((b*8+c)*64+h)
  int h = idx & 63, c = (idx >> 6) & 7, b = idx >> 9;
  int tid = threadIdx.x, lane = tid & 63, w = tid >> 6;
  int q = lane >> 4, ln = lane & 15;
  __shared__ __align__(16) bf16 sBT[2 * 128 * 32];  // [(kc*128+n)*32 + (s&31)]
  __shared__ __align__(16) bf16 sXT[2 * 64 * 32];   // [(kc*64+p)*32 + (s&31)]
  long caBase = ((long)(b * 64 + h) * 8 + c) * 256;
  float aLast = cumA[caBase + 255];
  long rowBase = (long)b * SEQ + c * CHUNK;
  floatx4 acc[2][4] = {};
  for (int s0 = 0; s0 < 256; s0 += 64) {
    __syncthreads();
    // stage B^T (transpose during write; 8 scalar b16 writes per bf16x8 read)
    for (int i = tid; i < 1024; i += 256) {
      int sl = i >> 4, n0 = (i & 15) * 8;
      bf16x8 v = *(const bf16x8*)(conv + (rowBase + s0 + sl) * CONV_DIM + INTER + n0);
      int base = ((sl >> 5) * 128 + n0) * 32 + (sl & 31);
#pragma unroll
      for (int jj = 0; jj < 8; jj++) sBT[base + jj * 32] = v[jj];
    }
    // stage (x*w)^T
    for (int i = tid; i < 512; i += 256) {
      int sl = i >> 3, p0 = (i & 7) * 8;
      long row = rowBase + s0 + sl;
      float wgt = __expf(aLast - cumA[caBase + s0 + sl]) * dtb[row * NUMH + h];
      bf16x8 v = *(const bf16x8*)(conv + row * CONV_DIM + h * HDIM + p0);
      int base = ((sl >> 5) * 64 + p0) * 32 + (sl & 31);
#pragma unroll
      for (int jj = 0; jj < 8; jj++) sXT[base + jj * 32] = (bf16)((float)v[jj] * wgt);
    }
    __syncthreads();
#pragma unroll
    for (int kc = 0; kc < 2; kc++) {
      bf16x8 af[2], bg[4];
#pragma unroll
      for (int mi = 0; mi < 2; mi++)
        af[mi] = *(const bf16x8*)(sBT + (kc * 128 + w * 32 + mi * 16 + ln) * 32 + q * 8);
#pragma unroll
      for (int ni = 0; ni < 4; ni++)
        bg[ni] = *(const bf16x8*)(sXT + (kc * 64 + ni * 16 + ln) * 32 + q * 8);
#pragma unroll
      for (int mi = 0; mi < 2; mi++)
#pragma unroll
        for (int ni = 0; ni < 4; ni++)
          acc[mi][ni] = __builtin_amdgcn_mfma_f32_16x16x32_bf16(
              af[mi], bg[ni], acc[mi][ni], 0, 0, 0);
    }
  }
  float* Sp = S + ((long)idx << 13);
#pragma unroll
  for (int mi = 0; mi < 2; mi++)
#pragma unroll
    for (int ni = 0; ni < 4; ni++) {
      int p = ni * 16 + ln;
#pragma unroll
      for (int r = 0; r < 4; r++) {
        int n = w * 32 + mi * 16 + q * 4 + r;
        Sp[n * 64 + p] = acc[mi][ni][r];
      }
    }
}

// ---------------------------------------- inter-chunk recurrence (b,h,kq)
__global__ __launch_bounds__(256) void recur_kernel(
    const float* __restrict__ S, const float* __restrict__ cumA,
    float* __restrict__ P) {
  int bh = blockIdx.x, kq = blockIdx.y;
  int b = bh >> 6, h = bh & 63;
  int tid = threadIdx.x;
  float p[8];
#pragma unroll
  for (int k = 0; k < 8; k++) p[k] = 0.f;
  for (int c = 0; c < 8; c++) {
    long blk = ((long)(b * 8 + c) * 64 + h) << 13;
#pragma unroll
    for (int k = 0; k < 8; k++) P[blk + (kq * 8 + k) * 256 + tid] = p[k];
    float e = __expf(cumA[((long)bh * 8 + c) * 256 + 255]);
#pragma unroll
    for (int k = 0; k < 8; k++) p[k] = S[blk + (kq * 8 + k) * 256 + tid] + e * p[k];
  }
}

// ------------------------------------------------ Y = diag + off + D*x (MFMA)
__global__ __launch_bounds__(256, 2) void y_kernel(
    const bf16* __restrict__ conv, const float* __restrict__ dtb,
    const float* __restrict__ cumA, const float* __restrict__ G,
    const float* __restrict__ P, const float* __restrict__ D,
    bf16* __restrict__ ybuf) {
  int idx = blockIdx.x;  // ((b*8+c)*64+h)
  int h = idx & 63, c = (idx >> 6) & 7, b = idx >> 9;
  int tid = threadIdx.x, lane = tid & 63, w = tid >> 6;
  int q = lane >> 4, ln = lane & 15;
  __shared__ __align__(16) bf16 sPT[128 * 64];   // ((n>>5)*64+p)*32+(n&31)
  __shared__ __align__(16) bf16 sXT[256 * 64];   // ((s>>5)*64+p)*32+(s&31)
  __shared__ float scA[256];
  long caBase = ((long)(b * 64 + h) * 8 + c) * 256;
  long rowBase = (long)b * SEQ + c * CHUNK;
  const float* Gbase = G + ((long)(b * 8 + c) << 16);

  scA[tid] = cumA[caBase + tid];
  {
    const float* Pblk = P + ((long)idx << 13);
    int n = tid >> 1;
    int p0 = (tid & 1) * 32;
    int nc = (n >> 5) * 64, nk = n & 31;
#pragma unroll
    for (int pp = 0; pp < 32; pp += 4) {
      floatx4 v = *(const floatx4*)(Pblk + n * 64 + p0 + pp);
#pragma unroll
      for (int j = 0; j < 4; j++)
        sPT[(nc + p0 + pp + j) * 32 + nk] = (bf16)v[j];
    }
  }
  {
    int s = tid;
    long row = rowBase + s;
    float dt = dtb[row * NUMH + h];
    int sc = (s >> 5) * 64, sk = s & 31;
    const bf16* xr = conv + row * CONV_DIM + h * HDIM;
#pragma unroll
    for (int p0 = 0; p0 < 64; p0 += 8) {
      bf16x8 xv = *(const bf16x8*)(xr + p0);
#pragma unroll
      for (int j = 0; j < 8; j++)
        sXT[(sc + p0 + j) * 32 + sk] = (bf16)((float)xv[j] * dt);
    }
  }
  __syncthreads();

  floatx4 acc[4][4] = {};

  // phase 1: Y_off = C @ P^T
  const bf16* Cbase = conv + (rowBase + w * 64) * CONV_DIM + INTER + STATE;
  for (int k0 = 0; k0 < 128; k0 += 32) {
    bf16x8 af[4], bg[4];
#pragma unroll
    for (int mi = 0; mi < 4; mi++)
      af[mi] = *(const bf16x8*)(Cbase + (long)(mi * 16 + ln) * CONV_DIM + k0 + q * 8);
#pragma unroll
    for (int ni = 0; ni < 4; ni++)
      bg[ni] = *(const bf16x8*)(sPT + ((k0 >> 5) * 64 + ni * 16 + ln) * 32 + q * 8);
#pragma unroll
    for (int mi = 0; mi < 4; mi++)
#pragma unroll
      for (int ni = 0; ni < 4; ni++)
        acc[mi][ni] = __builtin_amdgcn_mfma_f32_16x16x32_bf16(
            af[mi], bg[ni], acc[mi][ni], 0, 0, 0);
  }
#pragma unroll
  for (int mi = 0; mi < 4; mi++)
#pragma unroll
    for (int r = 0; r < 4; r++) {
      float e = __expf(scA[w * 64 + mi * 16 + q * 4 + r]);
#pragma unroll
      for (int ni = 0; ni < 4; ni++) acc[mi][ni][r] *= e;
    }

  // phase 2: Y_diag = M @ X
  for (int sb = 0; sb <= w; sb++) {
#pragma unroll
    for (int kk = 0; kk < 64; kk += 32) {
      int s0 = sb * 64 + kk;
      bf16x8 af[4], bg[4];
#pragma unroll
      for (int mi = 0; mi < 4; mi++) {
        int t = w * 64 + mi * 16 + ln;
        float cAt = scA[t];
        const float* Gr = Gbase + (long)t * 256 + s0 + q * 8;
        floatx4 g0 = *(const floatx4*)Gr;
        floatx4 g1 = *(const floatx4*)(Gr + 4);
        bf16x8 m;
#pragma unroll
        for (int j = 0; j < 4; j++) {
          int s = s0 + q * 8 + j;
          float v = g0[j] * __expf(cAt - scA[s]);
          m[j] = (bf16)((s <= t) ? v : 0.f);
        }
#pragma unroll
        for (int j = 4; j < 8; j++) {
          int s = s0 + q * 8 + j;
          float v = g1[j - 4] * __expf(cAt - scA[s]);
          m[j] = (bf16)((s <= t) ? v : 0.f);
        }
        af[mi] = m;
      }
#pragma unroll
      for (int ni = 0; ni < 4; ni++)
        bg[ni] = *(const bf16x8*)(sXT + ((s0 >> 5) * 64 + ni * 16 + ln) * 32 + q * 8);
#pragma unroll
      for (int mi = 0; mi < 4; mi++)
#pragma unroll
        for (int ni = 0; ni < 4; ni++)
          acc[mi][ni] = __builtin_amdgcn_mfma_f32_16x16x32_bf16(
              af[mi], bg[ni], acc[mi][ni], 0, 0, 0);
    }
  }

  float d = D[h];
#pragma unroll
  for (int mi = 0; mi < 4; mi++)
#pragma unroll
    for (int ni = 0; ni < 4; ni++) {
      int col = ni * 16 + ln;
#pragma unroll
      for (int r = 0; r < 4; r++) {
        long row = rowBase + w * 64 + mi * 16 + q * 4 + r;
        float xv = (float)conv[row * CONV_DIM + h * HDIM + col];
        ybuf[row * INTER + h * HDIM + col] = (bf16)(acc[mi][ni][r] + d * xv);
      }
    }
}

// ------------------------------------------------------- gated RMSNorm->bf16
__global__ __launch_bounds__(256) void rmsnorm_kernel(
    const bf16* __restrict__ ybuf, const bf16* __restrict__ proj,
    const float* __restrict__ nw, bf16* __restrict__ gb) {
  long row = blockIdx.x;
  int tid = threadIdx.x;
  float gv[16];
  float ss = 0.f;
#pragma unroll
  for (int k = 0; k < 16; k++) {
    int i = k * 256 + tid;
    float y = (float)ybuf[row * INTER + i];
    float gt = (float)proj[row * PROJ_PAD + i];
    float g = y * (gt / (1.f + expf(-gt)));
    gv[k] = g;
    ss += g * g;
  }
#pragma unroll
  for (int off = 32; off > 0; off >>= 1) ss += __shfl_down(ss, off, 64);
  __shared__ float red[4];
  if ((tid & 63) == 0) red[tid >> 6] = ss;
  __syncthreads();
  float tot = red[0] + red[1] + red[2] + red[3];
  float scale = rsqrtf(tot * (1.f / 4096.f) + 1e-5f);
#pragma unroll
  for (int k = 0; k < 16; k++) {
    int i = k * 256 + tid;
    gb[row * INTER + i] = (bf16)(gv[k] * scale * nw[i]);
  }
}

// ============================================================== launch
extern "C" void kernel_launch(void* const* d_in, const int* in_sizes, int n_in,
                              void* d_out, int out_size, void* d_ws, size_t ws_size,
                              hipStream_t stream) {
  const float* hs   = (const float*)d_in[0];
  const float* ipw  = (const float*)d_in[1];
  const float* ipb  = (const float*)d_in[2];
  const float* cw   = (const float*)d_in[3];
  const float* dtbi = (const float*)d_in[4];
  const float* alog = (const float*)d_in[5];
  const float* Dp   = (const float*)d_in[6];
  const float* nw   = (const float*)d_in[7];
  const float* opw  = (const float*)d_in[8];
  const float* opb  = (const float*)d_in[9];
  float* out = (float*)d_out;

  char* ws = (char*)d_ws;
  bf16*  hsb   = (bf16*)(ws + 0);
  bf16*  wb    = (bf16*)(ws + 16777216);
  float* S     = (float*)(ws + 0);           // overlays hsb+wb (dead after gemm1)
  bf16*  ybuf  = (bf16*)(ws + 0);            // overlays S (dead after recur)
  bf16*  owb   = (bf16*)(ws + 35127296);     // overlays upper wb (dead after gemm1)
  bf16*  proj  = (bf16*)(ws + 51904512);
  bf16*  conv  = (bf16*)(ws + 122159104);
  float* dtraw = (float*)(ws + 157810688);
  float* dtb   = (float*)(ws + 158859264);
  float* cumA  = (float*)(ws + 159907840);
  float* G     = (float*)(ws + 160956416);
  float* P     = (float*)(ws + 165150720);
  bf16*  gb    = (bf16*)(ws + 165150720);    // overlays P (dead after y_kernel)

  cvt_bf16_kernel<<<8192, 256, 0, stream>>>(hs, hsb, (long)ROWS * HIDDEN, (long)ROWS * HIDDEN);
  cvt_bf16_kernel<<<17152, 256, 0, stream>>>(ipw, wb, (long)PROJ_PAD * HIDDEN, (long)PROJ_N * HIDDEN);

  gemm_bt_kernel<<<(PROJ_PAD / 128) * (ROWS / 128), 256, 0, stream>>>(
      hsb, wb, ipb, proj, nullptr, dtraw, ROWS, PROJ_PAD, HIDDEN, PROJ_N, DT_COL0);

  cvt_bf16_kernel<<<8192, 256, 0, stream>>>(opw, owb, (long)HIDDEN * INTER, (long)HIDDEN * INTER);

  conv_silu_kernel<<<17408, 256, 0, stream>>>(proj, cw, conv);

  dt_scan_kernel<<<1024, 256, 0, stream>>>(dtraw, dtbi, alog, dtb, cumA);

  g_kernel<<<dim3(16, 4, 4), 256, 0, stream>>>(conv, G);

  states_kernel<<<1024, 256, 0, stream>>>(conv, dtb, cumA, S);

  recur_kernel<<<dim3(128, 4), 256, 0, stream>>>(S, cumA, P);

  y_kernel<<<1024, 256, 0, stream>>>(conv, dtb, cumA, G, P, Dp, ybuf);

  rmsnorm_kernel<<<4096, 256, 0, stream>>>(ybuf, proj, nw, gb);

  gemm_bt_kernel<<<(HIDDEN / 128) * (ROWS / 128), 256, 0, stream>>>(
      gb, owb, opb, nullptr, out, nullptr, ROWS, HIDDEN, INTER, HIDDEN, 1 << 30);
}

// Round 5
// 658.077 us; speedup vs baseline: 1.7663x; 1.0954x over previous
//
#include <hip/hip_runtime.h>

typedef __bf16 bf16;
typedef __bf16 bf16x8 __attribute__((ext_vector_type(8)));
typedef __bf16 bf16x4 __attribute__((ext_vector_type(4)));
typedef float  floatx4 __attribute__((ext_vector_type(4)));

#define HIDDEN   2048
#define NUMH     64
#define HDIM     64
#define STATE    128
#define INTER    4096
#define CONV_DIM 4352
#define PROJ_N   8512
#define PROJ_PAD 8576
#define SEQ      2048
#define BATCH    2
#define CHUNK    256
#define NCHUNK   8
#define ROWS     4096   // BATCH*SEQ
#define DT_COL0  8448   // INTER + CONV_DIM

// async global->LDS, 16B per lane, LDS dest = wave-uniform base + lane*16
#define GLDS(gp, lp) __builtin_amdgcn_global_load_lds(                      \
    (const __attribute__((address_space(1))) void*)(gp),                    \
    (__attribute__((address_space(3))) void*)(lp), 16, 0, 0)

// ---------------------------------------------------------------- f32 -> bf16
__global__ __launch_bounds__(256) void cvt_bf16_kernel(
    const float* __restrict__ in, bf16* __restrict__ out, long n, long srcn) {
  long i = ((long)blockIdx.x * 256 + threadIdx.x) * 4;
  if (i >= n) return;
  if (i + 3 < srcn) {
    const float* p = in + i;
    bf16x4 o;
    o[0] = (bf16)p[0]; o[1] = (bf16)p[1]; o[2] = (bf16)p[2]; o[3] = (bf16)p[3];
    *(bf16x4*)(out + i) = o;
  } else {
    for (int j = 0; j < 4; j++) {
      float v = (i + j < srcn) ? in[i + j] : 0.f;
      out[i + j] = (bf16)v;
    }
  }
}

// ------------------------------------------------------- bf16 MFMA GEMM (BT)
// C[M][N] = A[M][K] @ B[N][K]^T + bias ; XCD-striped raster; BK=64 K-loop
// staged as two [128][32] halves (keeps GLDS contiguity contract AND the
// proven BK=32 frag-read bank pattern). 8 GLDS in flight per barrier window.
__global__ __launch_bounds__(256, 2) void gemm_bt_kernel(
    const bf16* __restrict__ A, const bf16* __restrict__ B,
    const float* __restrict__ bias, bf16* __restrict__ Cb,
    float* __restrict__ Cf, float* __restrict__ ds,
    int M, int N, int K, int bias_n, int dt0) {
  __shared__ __align__(16) bf16 lA[2 * 128 * 32];
  __shared__ __align__(16) bf16 lB[2 * 128 * 32];
  const int tid  = threadIdx.x;
  const int lane = tid & 63;
  const int wave = tid >> 6;
  const int gm = M >> 7;
  const int id = blockIdx.x;
  const int xcd = id & 7;
  const int j = id >> 3;
  const int mstripe = gm >> 3;
  const int mb = xcd * mstripe + (j % mstripe);
  const int nb = j / mstripe;
  const int m0 = mb * 128;
  const int n0 = nb * 128;
  const int wm = (wave >> 1) * 64;
  const int wn = (wave & 1) * 64;
  const int q  = lane >> 4;     // 0..3
  const int ln = lane & 15;
  const int r0 = tid >> 2;      // 0..63
  const int c0 = (tid & 3) * 8; // 0,8,16,24

  floatx4 acc[4][4] = {};

  const bf16* Ap = A + (long)(m0 + r0) * K + c0;
  const bf16* Bp = B + (long)(n0 + r0) * K + c0;
  bf16* lAw = lA + wave * 512;   // wave-uniform LDS base (lane*16B appended)
  bf16* lBw = lB + wave * 512;

  for (int k0 = 0; k0 < K; k0 += 64) {
    __syncthreads();
    GLDS(Ap + k0, lAw);
    GLDS(Ap + (long)64 * K + k0, lAw + 2048);
    GLDS(Ap + k0 + 32, lAw + 4096);
    GLDS(Ap + (long)64 * K + k0 + 32, lAw + 6144);
    GLDS(Bp + k0, lBw);
    GLDS(Bp + (long)64 * K + k0, lBw + 2048);
    GLDS(Bp + k0 + 32, lBw + 4096);
    GLDS(Bp + (long)64 * K + k0 + 32, lBw + 6144);
    __syncthreads();
#pragma unroll
    for (int kc = 0; kc < 2; kc++) {
      bf16x8 af[4], bg[4];
#pragma unroll
      for (int i = 0; i < 4; i++) {
        af[i] = *(const bf16x8*)(lA + kc * 4096 + (wm + i * 16 + ln) * 32 + q * 8);
        bg[i] = *(const bf16x8*)(lB + kc * 4096 + (wn + i * 16 + ln) * 32 + q * 8);
      }
#pragma unroll
      for (int mi = 0; mi < 4; mi++)
#pragma unroll
        for (int ni = 0; ni < 4; ni++)
          acc[mi][ni] = __builtin_amdgcn_mfma_f32_16x16x32_bf16(
              af[mi], bg[ni], acc[mi][ni], 0, 0, 0);
    }
  }

#pragma unroll
  for (int mi = 0; mi < 4; mi++) {
#pragma unroll
    for (int ni = 0; ni < 4; ni++) {
      int col = n0 + wn + ni * 16 + ln;
      float bv = (col < bias_n) ? bias[col] : 0.f;
#pragma unroll
      for (int r = 0; r < 4; r++) {
        int row = m0 + wm + mi * 16 + q * 4 + r;
        float v = acc[mi][ni][r] + bv;
        if (Cb) Cb[(long)row * N + col] = (bf16)v;
        else    Cf[(long)row * N + col] = v;
        if (ds && col >= dt0 && col < dt0 + 64)
          ds[(long)row * 64 + (col - dt0)] = v;
      }
    }
  }
}

// ------------------------------------------------------- causal conv4 + SiLU
__global__ __launch_bounds__(256) void conv_silu_kernel(
    const bf16* __restrict__ proj, const float* __restrict__ cw,
    bf16* __restrict__ out) {
  long i = ((long)blockIdx.x * 256 + threadIdx.x) * 4;
  if (i >= (long)ROWS * CONV_DIM) return;
  int ch = (int)(i % CONV_DIM);        // multiple of 4
  long bl = i / CONV_DIM;
  int l = (int)(bl & (SEQ - 1));
  const bf16* p = proj + bl * PROJ_PAD + INTER + ch;
  float a[4] = {0.f, 0.f, 0.f, 0.f};
#pragma unroll
  for (int tap = 0; tap < 4; tap++) {
    int back = 3 - tap;
    if (l >= back) {
      bf16x4 v = *(const bf16x4*)(p - (long)back * PROJ_PAD);
#pragma unroll
      for (int j = 0; j < 4; j++) a[j] += (float)v[j] * cw[(ch + j) * 4 + tap];
    }
  }
  bf16x4 o;
#pragma unroll
  for (int j = 0; j < 4; j++) {
    float s = a[j] / (1.f + expf(-a[j]));
    o[j] = (bf16)s;
  }
  *(bf16x4*)(out + i) = o;
}

// ---------------------------------------------- dt softplus + per-chunk scan
__global__ __launch_bounds__(256) void dt_scan_kernel(
    const float* __restrict__ dtraw, const float* __restrict__ dt_bias,
    const float* __restrict__ A_log, float* __restrict__ dtb,
    float* __restrict__ cumA) {
  int idx = blockIdx.x;
  int c = idx & 7, h = (idx >> 3) & 63, b = idx >> 9;
  int s = threadIdx.x;
  long row = (long)b * SEQ + c * CHUNK + s;
  float x = dtraw[row * NUMH + h] + dt_bias[h];
  float dt = (x > 20.f) ? x : log1pf(expf(x));
  dtb[row * NUMH + h] = dt;
  float dA = -expf(A_log[h]) * dt;
  __shared__ float sc[256];
  sc[s] = dA;
  __syncthreads();
  for (int off = 1; off < 256; off <<= 1) {
    float v = (s >= off) ? sc[s - off] : 0.f;
    __syncthreads();
    sc[s] += v;
    __syncthreads();
  }
  cumA[(long)idx * 256 + s] = sc[s];
}

// ------------------------------------------------- G = C @ B^T  (MFMA)
__global__ __launch_bounds__(256, 2) void g_kernel(
    const bf16* __restrict__ conv, float* __restrict__ G) {
  int bc = blockIdx.x, tt = blockIdx.y, sb = blockIdx.z;
  if (sb > tt) return;  // upper triangle never read
  int b = bc >> 3, c = bc & 7;
  int tid = threadIdx.x, lane = tid & 63, w = tid >> 6;
  int q = lane >> 4, ln = lane & 15;
  __shared__ __align__(16) bf16 sCg[4 * 64 * 32];  // [(kc*64+t)*32 + (n&31)]
  __shared__ __align__(16) bf16 sBg[4 * 64 * 32];
  long rowBase = (long)b * SEQ + c * CHUNK;
  for (int i = tid; i < 1024; i += 256) {
    int r = i >> 4, n0 = (i & 15) * 8;
    int base = ((n0 >> 5) * 64 + r) * 32 + (n0 & 31);
    bf16x8 cv = *(const bf16x8*)(conv + (rowBase + tt * 64 + r) * CONV_DIM + INTER + STATE + n0);
    *(bf16x8*)(sCg + base) = cv;
    bf16x8 bv = *(const bf16x8*)(conv + (rowBase + sb * 64 + r) * CONV_DIM + INTER + n0);
    *(bf16x8*)(sBg + base) = bv;
  }
  __syncthreads();
  floatx4 acc[4] = {};
#pragma unroll
  for (int kc = 0; kc < 4; kc++) {
    bf16x8 af = *(const bf16x8*)(sCg + (kc * 64 + w * 16 + ln) * 32 + q * 8);
#pragma unroll
    for (int ni = 0; ni < 4; ni++) {
      bf16x8 bg = *(const bf16x8*)(sBg + (kc * 64 + ni * 16 + ln) * 32 + q * 8);
      acc[ni] = __builtin_amdgcn_mfma_f32_16x16x32_bf16(af, bg, acc[ni], 0, 0, 0);
    }
  }
  float* Gb = G + ((long)bc << 16);
#pragma unroll
  for (int ni = 0; ni < 4; ni++) {
    int s = sb * 64 + ni * 16 + ln;
#pragma unroll
    for (int r = 0; r < 4; r++) {
      int t = tt * 64 + w * 16 + q * 4 + r;
      Gb[(long)t * 256 + s] = acc[ni][r];
    }
  }
}

// --------------------------------------- per-chunk states S = B^T·(x·w) MFMA
__global__ __launch_bounds__(256, 2) void states_kernel(
    const bf16* __restrict__ conv, const float* __restrict__ dtb,
    const float* __restrict__ cumA, float* __restrict__ S) {
  int idx = blockIdx.x;  // ((b*8+c)*64+h)
  int h = idx & 63, c = (idx >> 6) & 7, b = idx >> 9;
  int tid = threadIdx.x, lane = tid & 63, w = tid >> 6;
  int q = lane >> 4, ln = lane & 15;
  __shared__ __align__(16) bf16 sBT[2 * 128 * 32];  // [(kc*128+n)*32 + (s&31)]
  __shared__ __align__(16) bf16 sXT[2 * 64 * 32];   // [(kc*64+p)*32 + (s&31)]
  long caBase = ((long)(b * 64 + h) * 8 + c) * 256;
  float aLast = cumA[caBase + 255];
  long rowBase = (long)b * SEQ + c * CHUNK;
  floatx4 acc[2][4] = {};
  for (int s0 = 0; s0 < 256; s0 += 64) {
    __syncthreads();
    for (int i = tid; i < 1024; i += 256) {
      int sl = i >> 4, n0 = (i & 15) * 8;
      bf16x8 v = *(const bf16x8*)(conv + (rowBase + s0 + sl) * CONV_DIM + INTER + n0);
      int base = ((sl >> 5) * 128 + n0) * 32 + (sl & 31);
#pragma unroll
      for (int jj = 0; jj < 8; jj++) sBT[base + jj * 32] = v[jj];
    }
    for (int i = tid; i < 512; i += 256) {
      int sl = i >> 3, p0 = (i & 7) * 8;
      long row = rowBase + s0 + sl;
      float wgt = __expf(aLast - cumA[caBase + s0 + sl]) * dtb[row * NUMH + h];
      bf16x8 v = *(const bf16x8*)(conv + row * CONV_DIM + h * HDIM + p0);
      int base = ((sl >> 5) * 64 + p0) * 32 + (sl & 31);
#pragma unroll
      for (int jj = 0; jj < 8; jj++) sXT[base + jj * 32] = (bf16)((float)v[jj] * wgt);
    }
    __syncthreads();
#pragma unroll
    for (int kc = 0; kc < 2; kc++) {
      bf16x8 af[2], bg[4];
#pragma unroll
      for (int mi = 0; mi < 2; mi++)
        af[mi] = *(const bf16x8*)(sBT + (kc * 128 + w * 32 + mi * 16 + ln) * 32 + q * 8);
#pragma unroll
      for (int ni = 0; ni < 4; ni++)
        bg[ni] = *(const bf16x8*)(sXT + (kc * 64 + ni * 16 + ln) * 32 + q * 8);
#pragma unroll
      for (int mi = 0; mi < 2; mi++)
#pragma unroll
        for (int ni = 0; ni < 4; ni++)
          acc[mi][ni] = __builtin_amdgcn_mfma_f32_16x16x32_bf16(
              af[mi], bg[ni], acc[mi][ni], 0, 0, 0);
    }
  }
  float* Sp = S + ((long)idx << 13);
#pragma unroll
  for (int mi = 0; mi < 2; mi++)
#pragma unroll
    for (int ni = 0; ni < 4; ni++) {
      int p = ni * 16 + ln;
#pragma unroll
      for (int r = 0; r < 4; r++) {
        int n = w * 32 + mi * 16 + q * 4 + r;
        Sp[n * 64 + p] = acc[mi][ni][r];
      }
    }
}

// ---------------------------------------- inter-chunk recurrence (b,h,kq)
__global__ __launch_bounds__(256) void recur_kernel(
    const float* __restrict__ S, const float* __restrict__ cumA,
    float* __restrict__ P) {
  int bh = blockIdx.x, kq = blockIdx.y;
  int b = bh >> 6, h = bh & 63;
  int tid = threadIdx.x;
  float p[8];
#pragma unroll
  for (int k = 0; k < 8; k++) p[k] = 0.f;
  for (int c = 0; c < 8; c++) {
    long blk = ((long)(b * 8 + c) * 64 + h) << 13;
#pragma unroll
    for (int k = 0; k < 8; k++) P[blk + (kq * 8 + k) * 256 + tid] = p[k];
    float e = __expf(cumA[((long)bh * 8 + c) * 256 + 255]);
#pragma unroll
    for (int k = 0; k < 8; k++) p[k] = S[blk + (kq * 8 + k) * 256 + tid] + e * p[k];
  }
}

// ------------------------------------------------ Y = diag + off + D*x (MFMA)
// off-diag decay factored: exp(cAt-cAs) = exp(cAt-cAend(sb)) * sE[s], both <=1
__global__ __launch_bounds__(256, 2) void y_kernel(
    const bf16* __restrict__ conv, const float* __restrict__ dtb,
    const float* __restrict__ cumA, const float* __restrict__ G,
    const float* __restrict__ P, const float* __restrict__ D,
    bf16* __restrict__ ybuf) {
  int idx = blockIdx.x;  // ((b*8+c)*64+h)
  int h = idx & 63, c = (idx >> 6) & 7, b = idx >> 9;
  int tid = threadIdx.x, lane = tid & 63, w = tid >> 6;
  int q = lane >> 4, ln = lane & 15;
  __shared__ __align__(16) bf16 sPT[128 * 64];   // ((n>>5)*64+p)*32+(n&31)
  __shared__ __align__(16) bf16 sXT[256 * 64];   // ((s>>5)*64+p)*32+(s&31)
  __shared__ float scA[256];
  __shared__ float sE[256];                      // exp(cA[s|63] - cA[s]) <= 1
  long caBase = ((long)(b * 64 + h) * 8 + c) * 256;
  long rowBase = (long)b * SEQ + c * CHUNK;
  const float* Gbase = G + ((long)(b * 8 + c) << 16);

  float myA = cumA[caBase + tid];
  scA[tid] = myA;
  {
    const float* Pblk = P + ((long)idx << 13);
    int n = tid >> 1;
    int p0 = (tid & 1) * 32;
    int nc = (n >> 5) * 64, nk = n & 31;
#pragma unroll
    for (int pp = 0; pp < 32; pp += 4) {
      floatx4 v = *(const floatx4*)(Pblk + n * 64 + p0 + pp);
#pragma unroll
      for (int j = 0; j < 4; j++)
        sPT[(nc + p0 + pp + j) * 32 + nk] = (bf16)v[j];
    }
  }
  {
    int s = tid;
    long row = rowBase + s;
    float dt = dtb[row * NUMH + h];
    int sc = (s >> 5) * 64, sk = s & 31;
    const bf16* xr = conv + row * CONV_DIM + h * HDIM;
#pragma unroll
    for (int p0 = 0; p0 < 64; p0 += 8) {
      bf16x8 xv = *(const bf16x8*)(xr + p0);
#pragma unroll
      for (int j = 0; j < 8; j++)
        sXT[(sc + p0 + j) * 32 + sk] = (bf16)((float)xv[j] * dt);
    }
  }
  __syncthreads();
  sE[tid] = __expf(scA[tid | 63] - myA);

  floatx4 acc[4][4] = {};

  // phase 1: Y_off = C @ P^T
  const bf16* Cbase = conv + (rowBase + w * 64) * CONV_DIM + INTER + STATE;
  for (int k0 = 0; k0 < 128; k0 += 32) {
    bf16x8 af[4], bg[4];
#pragma unroll
    for (int mi = 0; mi < 4; mi++)
      af[mi] = *(const bf16x8*)(Cbase + (long)(mi * 16 + ln) * CONV_DIM + k0 + q * 8);
#pragma unroll
    for (int ni = 0; ni < 4; ni++)
      bg[ni] = *(const bf16x8*)(sPT + ((k0 >> 5) * 64 + ni * 16 + ln) * 32 + q * 8);
#pragma unroll
    for (int mi = 0; mi < 4; mi++)
#pragma unroll
      for (int ni = 0; ni < 4; ni++)
        acc[mi][ni] = __builtin_amdgcn_mfma_f32_16x16x32_bf16(
            af[mi], bg[ni], acc[mi][ni], 0, 0, 0);
  }
#pragma unroll
  for (int mi = 0; mi < 4; mi++)
#pragma unroll
    for (int r = 0; r < 4; r++) {
      float e = __expf(scA[w * 64 + mi * 16 + q * 4 + r]);
#pragma unroll
      for (int ni = 0; ni < 4; ni++) acc[mi][ni][r] *= e;
    }
  __syncthreads();  // sE visible to all waves

  // phase 2a: off-diagonal s-blocks (factored decay, no per-element expf)
  for (int sb = 0; sb < w; sb++) {
    float Rm[4];
#pragma unroll
    for (int mi = 0; mi < 4; mi++)
      Rm[mi] = __expf(scA[w * 64 + mi * 16 + ln] - scA[sb * 64 + 63]);
#pragma unroll
    for (int kk = 0; kk < 64; kk += 32) {
      int s0 = sb * 64 + kk;
      bf16x8 af[4], bg[4];
#pragma unroll
      for (int mi = 0; mi < 4; mi++) {
        int t = w * 64 + mi * 16 + ln;
        const float* Gr = Gbase + (long)t * 256 + s0 + q * 8;
        floatx4 g0 = *(const floatx4*)Gr;
        floatx4 g1 = *(const floatx4*)(Gr + 4);
        bf16x8 m;
#pragma unroll
        for (int j = 0; j < 4; j++)
          m[j] = (bf16)(g0[j] * Rm[mi] * sE[s0 + q * 8 + j]);
#pragma unroll
        for (int j = 4; j < 8; j++)
          m[j] = (bf16)(g1[j - 4] * Rm[mi] * sE[s0 + q * 8 + j]);
        af[mi] = m;
      }
#pragma unroll
      for (int ni = 0; ni < 4; ni++)
        bg[ni] = *(const bf16x8*)(sXT + ((s0 >> 5) * 64 + ni * 16 + ln) * 32 + q * 8);
#pragma unroll
      for (int mi = 0; mi < 4; mi++)
#pragma unroll
        for (int ni = 0; ni < 4; ni++)
          acc[mi][ni] = __builtin_amdgcn_mfma_f32_16x16x32_bf16(
              af[mi], bg[ni], acc[mi][ni], 0, 0, 0);
    }
  }

  // phase 2b: diagonal s-block (per-element expf + causal mask)
  {
    int sb = w;
#pragma unroll
    for (int kk = 0; kk < 64; kk += 32) {
      int s0 = sb * 64 + kk;
      bf16x8 af[4], bg[4];
#pragma unroll
      for (int mi = 0; mi < 4; mi++) {
        int t = w * 64 + mi * 16 + ln;
        float cAt = scA[t];
        const float* Gr = Gbase + (long)t * 256 + s0 + q * 8;
        floatx4 g0 = *(const floatx4*)Gr;
        floatx4 g1 = *(const floatx4*)(Gr + 4);
        bf16x8 m;
#pragma unroll
        for (int j = 0; j < 4; j++) {
          int s = s0 + q * 8 + j;
          float v = g0[j] * __expf(cAt - scA[s]);
          m[j] = (bf16)((s <= t) ? v : 0.f);
        }
#pragma unroll
        for (int j = 4; j < 8; j++) {
          int s = s0 + q * 8 + j;
          float v = g1[j - 4] * __expf(cAt - scA[s]);
          m[j] = (bf16)((s <= t) ? v : 0.f);
        }
        af[mi] = m;
      }
#pragma unroll
      for (int ni = 0; ni < 4; ni++)
        bg[ni] = *(const bf16x8*)(sXT + ((s0 >> 5) * 64 + ni * 16 + ln) * 32 + q * 8);
#pragma unroll
      for (int mi = 0; mi < 4; mi++)
#pragma unroll
        for (int ni = 0; ni < 4; ni++)
          acc[mi][ni] = __builtin_amdgcn_mfma_f32_16x16x32_bf16(
              af[mi], bg[ni], acc[mi][ni], 0, 0, 0);
    }
  }

  float d = D[h];
#pragma unroll
  for (int mi = 0; mi < 4; mi++)
#pragma unroll
    for (int ni = 0; ni < 4; ni++) {
      int col = ni * 16 + ln;
#pragma unroll
      for (int r = 0; r < 4; r++) {
        long row = rowBase + w * 64 + mi * 16 + q * 4 + r;
        float xv = (float)conv[row * CONV_DIM + h * HDIM + col];
        ybuf[row * INTER + h * HDIM + col] = (bf16)(acc[mi][ni][r] + d * xv);
      }
    }
}

// ------------------------------------------------------- gated RMSNorm->bf16
__global__ __launch_bounds__(256) void rmsnorm_kernel(
    const bf16* __restrict__ ybuf, const bf16* __restrict__ proj,
    const float* __restrict__ nw, bf16* __restrict__ gb) {
  long row = blockIdx.x;
  int tid = threadIdx.x;
  float gv[16];
  float ss = 0.f;
#pragma unroll
  for (int k = 0; k < 16; k++) {
    int i = k * 256 + tid;
    float y = (float)ybuf[row * INTER + i];
    float gt = (float)proj[row * PROJ_PAD + i];
    float g = y * (gt / (1.f + expf(-gt)));
    gv[k] = g;
    ss += g * g;
  }
#pragma unroll
  for (int off = 32; off > 0; off >>= 1) ss += __shfl_down(ss, off, 64);
  __shared__ float red[4];
  if ((tid & 63) == 0) red[tid >> 6] = ss;
  __syncthreads();
  float tot = red[0] + red[1] + red[2] + red[3];
  float scale = rsqrtf(tot * (1.f / 4096.f) + 1e-5f);
#pragma unroll
  for (int k = 0; k < 16; k++) {
    int i = k * 256 + tid;
    gb[row * INTER + i] = (bf16)(gv[k] * scale * nw[i]);
  }
}

// ============================================================== launch
extern "C" void kernel_launch(void* const* d_in, const int* in_sizes, int n_in,
                              void* d_out, int out_size, void* d_ws, size_t ws_size,
                              hipStream_t stream) {
  const float* hs   = (const float*)d_in[0];
  const float* ipw  = (const float*)d_in[1];
  const float* ipb  = (const float*)d_in[2];
  const float* cw   = (const float*)d_in[3];
  const float* dtbi = (const float*)d_in[4];
  const float* alog = (const float*)d_in[5];
  const float* Dp   = (const float*)d_in[6];
  const float* nw   = (const float*)d_in[7];
  const float* opw  = (const float*)d_in[8];
  const float* opb  = (const float*)d_in[9];
  float* out = (float*)d_out;

  char* ws = (char*)d_ws;
  bf16*  hsb   = (bf16*)(ws + 0);
  bf16*  wb    = (bf16*)(ws + 16777216);
  float* S     = (float*)(ws + 0);           // overlays hsb+wb (dead after gemm1)
  bf16*  ybuf  = (bf16*)(ws + 0);            // overlays S (dead after recur)
  bf16*  owb   = (bf16*)(ws + 35127296);     // overlays upper wb (dead after gemm1)
  bf16*  proj  = (bf16*)(ws + 51904512);
  bf16*  conv  = (bf16*)(ws + 122159104);
  float* dtraw = (float*)(ws + 157810688);
  float* dtb   = (float*)(ws + 158859264);
  float* cumA  = (float*)(ws + 159907840);
  float* G     = (float*)(ws + 160956416);
  float* P     = (float*)(ws + 165150720);
  bf16*  gb    = (bf16*)(ws + 165150720);    // overlays P (dead after y_kernel)

  cvt_bf16_kernel<<<8192, 256, 0, stream>>>(hs, hsb, (long)ROWS * HIDDEN, (long)ROWS * HIDDEN);
  cvt_bf16_kernel<<<17152, 256, 0, stream>>>(ipw, wb, (long)PROJ_PAD * HIDDEN, (long)PROJ_N * HIDDEN);

  gemm_bt_kernel<<<(PROJ_PAD / 128) * (ROWS / 128), 256, 0, stream>>>(
      hsb, wb, ipb, proj, nullptr, dtraw, ROWS, PROJ_PAD, HIDDEN, PROJ_N, DT_COL0);

  cvt_bf16_kernel<<<8192, 256, 0, stream>>>(opw, owb, (long)HIDDEN * INTER, (long)HIDDEN * INTER);

  conv_silu_kernel<<<17408, 256, 0, stream>>>(proj, cw, conv);

  dt_scan_kernel<<<1024, 256, 0, stream>>>(dtraw, dtbi, alog, dtb, cumA);

  g_kernel<<<dim3(16, 4, 4), 256, 0, stream>>>(conv, G);

  states_kernel<<<1024, 256, 0, stream>>>(conv, dtb, cumA, S);

  recur_kernel<<<dim3(128, 4), 256, 0, stream>>>(S, cumA, P);

  y_kernel<<<1024, 256, 0, stream>>>(conv, dtb, cumA, G, P, Dp, ybuf);

  rmsnorm_kernel<<<4096, 256, 0, stream>>>(ybuf, proj, nw, gb);

  gemm_bt_kernel<<<(HIDDEN / 128) * (ROWS / 128), 256, 0, stream>>>(
      gb, owb, opb, nullptr, out, nullptr, ROWS, HIDDEN, INTER, HIDDEN, 1 << 30);
}